// Round 5
// baseline (565.141 us; speedup 1.0000x reference)
//
#include <hip/hip_runtime.h>

// Problem dims
#define T_LEN 8192
#define H_DIM 2048
#define K_DIM 512
#define V_DIM 512
#define O_DIM 2048
#define CHUNK 64
#define NCHUNK 128   // T_LEN / CHUNK
#define CGROUP 64    // chunks per scan/intra pass (2 passes)

typedef short bf16x8 __attribute__((ext_vector_type(8)));
typedef float f32x4 __attribute__((ext_vector_type(4)));

__device__ __forceinline__ float b2f(unsigned short u) {
    unsigned int i = ((unsigned int)u) << 16;
    float f;
    __builtin_memcpy(&f, &i, 4);
    return f;
}
__device__ __forceinline__ unsigned short f2b(float f) {
    unsigned int i;
    __builtin_memcpy(&i, &f, 4);
    unsigned int r = (i + 0x7FFFu + ((i >> 16) & 1u)) >> 16;  // RNE
    return (unsigned short)r;
}
// NaN/inf firewall: fmaxf/fminf return the non-NaN operand, so NaN -> -1e30.
__device__ __forceinline__ float fw(float v) {
    return fminf(fmaxf(v, -1e30f), 1e30f);
}

// ---------------------------------------------------------------------------
// fp32 -> bf16 pack, 8 elements/thread. N multiple of 8.
__global__ __launch_bounds__(256) void conv2bf_k(const float* __restrict__ in,
                                                 unsigned short* __restrict__ out,
                                                 long N) {
    long i = ((long)blockIdx.x * 256 + threadIdx.x) * 8;
    if (i >= N) return;
    unsigned int w[4];
#pragma unroll
    for (int u = 0; u < 4; u++) {
        unsigned short lo = f2b(in[i + 2 * u]);
        unsigned short hi = f2b(in[i + 2 * u + 1]);
        w[u] = (unsigned int)lo | ((unsigned int)hi << 16);
    }
    uint4 pk; pk.x = w[0]; pk.y = w[1]; pk.z = w[2]; pk.w = w[3];
    *(uint4*)(out + i) = pk;
}

// ---------------------------------------------------------------------------
// Runtime C/D-layout probe for mfma_f32_16x16x32_bf16 (relative to our load
// convention). flag=0: acc[i] = D[row=q4*4+i][col=ln15]; flag=1: transposed.
__global__ __launch_bounds__(64) void probe_k(int* __restrict__ flag) {
    __shared__ unsigned short As[16 * 32];
    __shared__ unsigned short Bs[16 * 32];
    int tid = threadIdx.x;
    for (int idx = tid; idx < 512; idx += 64) {
        int r = idx >> 5, c = idx & 31;
        float av = (c == 0) ? (float)(r + 1) : (c == 1 ? 1.0f : 0.0f);
        float bv = (c == 0) ? 1.0f : (c == 1 ? (float)(1024 * (r + 1)) : 0.0f);
        As[r * 32 + c] = f2b(av);
        Bs[r * 32 + c] = f2b(bv);
    }
    __syncthreads();
    int ln15 = tid & 15, q4 = (tid & 63) >> 4;
    bf16x8 a = *(const bf16x8*)(As + ln15 * 32 + q4 * 8);
    bf16x8 b = *(const bf16x8*)(Bs + ln15 * 32 + q4 * 8);
    f32x4 acc = {0.f, 0.f, 0.f, 0.f};
    acc = __builtin_amdgcn_mfma_f32_16x16x32_bf16(a, b, acc, 0, 0, 0);
    bool h0 = true, h1 = true;
#pragma unroll
    for (int i = 0; i < 4; i++) {
        float e0 = (float)((q4 * 4 + i + 1) + 1024 * (ln15 + 1));
        float e1 = (float)((ln15 + 1) + 1024 * (q4 * 4 + i + 1));
        h0 = h0 && (acc[i] == e0);
        h1 = h1 && (acc[i] == e1);
    }
    unsigned long long b0 = __ballot(h0 ? 1 : 0);
    unsigned long long b1 = __ballot(h1 ? 1 : 0);
    if (tid == 0) *flag = (b0 == ~0ull) ? 0 : ((b1 == ~0ull) ? 1 : 0);
}

// ---------------------------------------------------------------------------
// Transpose to bf16: in[R][C] -> out[C][R]. DF=1: in is fp32; DF=0: bf16.
template <int DF>
__global__ __launch_bounds__(256) void transpose_k(const void* __restrict__ in,
                                                   unsigned short* __restrict__ out,
                                                   int R, int C) {
    __shared__ unsigned short tile[32][33];
    int br = blockIdx.x, bc = blockIdx.y;
    int tc = threadIdx.x & 31, tr = threadIdx.x >> 5;
#pragma unroll
    for (int i = 0; i < 4; i++) {
        int r = tr + 8 * i;
        long idx = (long)(br * 32 + r) * C + bc * 32 + tc;
        tile[r][tc] = DF ? f2b(((const float*)in)[idx]) : ((const unsigned short*)in)[idx];
    }
    __syncthreads();
#pragma unroll
    for (int i = 0; i < 4; i++) {
        int r = tr + 8 * i;
        out[(long)(bc * 32 + r) * R + br * 32 + tc] = tile[tc][r];
    }
}

// ---------------------------------------------------------------------------
// 128x128-tile bf16 GEMM, B given transposed ([N][K2], K-contiguous).
// out = act(A @ B^T + bias). ACT: 0 = none, 1 = sigmoid. bias is fp32.
template <int ACT, typename OutT>
__global__ __launch_bounds__(256) void gemm_bt(const unsigned short* __restrict__ A,
                                               const unsigned short* __restrict__ BT,
                                               const float* __restrict__ bias,
                                               OutT* __restrict__ out,
                                               int M, int N, int K,
                                               const int* __restrict__ flagp) {
    __shared__ unsigned short As[128 * 32];
    __shared__ unsigned short Bs[128 * 32];
    int fl = *flagp;
    int tid = threadIdx.x;
    int lane = tid & 63;
    int w = tid >> 6;
    int ln15 = lane & 15, q4 = lane >> 4;
    int wm = w >> 1, wn = w & 1;
    long m0 = (long)blockIdx.x * 128, n0 = (long)blockIdx.y * 128;

    f32x4 acc[4][4] = {};

    for (int kt = 0; kt < K; kt += 32) {
        bf16x8 ra[2], rb[2];
#pragma unroll
        for (int it = 0; it < 2; it++) {
            int chunk = it * 256 + tid;
            int row = chunk >> 2;
            int col = (chunk & 3) * 8;
            ra[it] = *(const bf16x8*)(A + (m0 + row) * (long)K + kt + col);
            rb[it] = *(const bf16x8*)(BT + (n0 + row) * (long)K + kt + col);
        }
        __syncthreads();
#pragma unroll
        for (int it = 0; it < 2; it++) {
            int chunk = it * 256 + tid;
            *(bf16x8*)(As + chunk * 8) = ra[it];
            *(bf16x8*)(Bs + chunk * 8) = rb[it];
        }
        __syncthreads();
        bf16x8 a[4], b[4];
#pragma unroll
        for (int i = 0; i < 4; i++)
            a[i] = *(const bf16x8*)(As + (wm * 64 + 16 * i + ln15) * 32 + q4 * 8);
#pragma unroll
        for (int j = 0; j < 4; j++)
            b[j] = *(const bf16x8*)(Bs + (wn * 64 + 16 * j + ln15) * 32 + q4 * 8);
#pragma unroll
        for (int i = 0; i < 4; i++)
#pragma unroll
            for (int j = 0; j < 4; j++)
                acc[i][j] = __builtin_amdgcn_mfma_f32_16x16x32_bf16(a[i], b[j], acc[i][j], 0, 0, 0);
    }

#pragma unroll
    for (int i = 0; i < 4; i++) {
#pragma unroll
        for (int j = 0; j < 4; j++) {
#pragma unroll
            for (int ii = 0; ii < 4; ii++) {
                int dm = fl ? ln15 : q4 * 4 + ii;
                int dn = fl ? q4 * 4 + ii : ln15;
                long m = m0 + wm * 64 + 16 * i + dm;
                long n = n0 + wn * 64 + 16 * j + dn;
                float v = fw(acc[i][j][ii] + bias[n]);
                if (ACT == 1) v = 1.0f / (1.0f + __expf(-v));
                if (sizeof(OutT) == 2)
                    out[m * N + n] = (OutT)f2b(v);
                else
                    out[m * N + n] = (OutT)v;
            }
        }
    }
}

// ---------------------------------------------------------------------------
// Per (chunk, dim): cumulative gate products. In-place q->q*P, k->k/P; writes
// khatT[d][t] = k * Pend/P (transposed), pend[c][d].
__global__ __launch_bounds__(256) void cumprod_k(const float* __restrict__ g,
                                                 unsigned short* __restrict__ q,
                                                 unsigned short* __restrict__ k,
                                                 unsigned short* __restrict__ khatT,
                                                 float* __restrict__ pend) {
    int c = blockIdx.x;
    int d = blockIdx.y * 256 + threadIdx.x;
    long base = (long)c * CHUNK * K_DIM + d;
    float P = 1.0f;
    for (int s = 0; s < CHUNK; s++) P = fmaxf(P * g[base + (long)s * K_DIM], 1e-37f);
    pend[c * K_DIM + d] = P;
    float Pend = P;
    P = 1.0f;
    for (int s8 = 0; s8 < CHUNK; s8 += 8) {
        unsigned int packed[4];
#pragma unroll
        for (int u = 0; u < 8; u++) {
            int s = s8 + u;
            long idx = base + (long)s * K_DIM;
            P = fmaxf(P * g[idx], 1e-37f);
            float qv = fw(b2f(q[idx]) * P);
            q[idx] = f2b(qv);
            float kv = b2f(k[idx]);
            float kt = kv / P;
            kt = fmaxf(fminf(kt, 3e37f), -3e37f);
            k[idx] = f2b(kt);
            float ratio = Pend / P;  // in (0,1]
            unsigned short kh = f2b(fw(kv * ratio));
            if (u & 1)
                packed[u >> 1] |= ((unsigned int)kh) << 16;
            else
                packed[u >> 1] = kh;
        }
        uint4 pk;
        pk.x = packed[0]; pk.y = packed[1]; pk.z = packed[2]; pk.w = packed[3];
        *(uint4*)(khatT + (long)d * T_LEN + c * CHUNK + s8) = pk;
    }
}

// ---------------------------------------------------------------------------
// Sequential chunk scan over [c0, cn). State carried fp32 in Sio ([K][V]);
// per chunk writes bf16 S-before into ST[(c - c0)] ([v][k], k contiguous).
__global__ __launch_bounds__(256) void scan_k(const unsigned short* __restrict__ khatT,
                                              const unsigned short* __restrict__ vT,
                                              const float* __restrict__ pend,
                                              unsigned short* __restrict__ ST,
                                              float* __restrict__ Sio,
                                              int c0, int cn,
                                              const int* __restrict__ flagp) {
    int fl = *flagp;
    int lane = threadIdx.x & 63, w = threadIdx.x >> 6;
    int ln15 = lane & 15, q4 = lane >> 4;
    int k0 = (blockIdx.x & 15) * 32 + (w & 1) * 16;
    int v0 = (blockIdx.x >> 4) * 32 + (w >> 1) * 16;
    f32x4 acc;
#pragma unroll
    for (int i = 0; i < 4; i++) {
        int dk = fl ? ln15 : q4 * 4 + i;
        int dv = fl ? q4 * 4 + i : ln15;
        acc[i] = Sio[(long)(k0 + dk) * V_DIM + v0 + dv];
    }
    for (int c = c0; c < cn; c++) {
        long cloc = c - c0;
        if (!fl) {
            uint2 pk;
            pk.x = (unsigned int)f2b(fw(acc[0])) | ((unsigned int)f2b(fw(acc[1])) << 16);
            pk.y = (unsigned int)f2b(fw(acc[2])) | ((unsigned int)f2b(fw(acc[3])) << 16);
            *(uint2*)(ST + (cloc * V_DIM + v0 + ln15) * K_DIM + k0 + q4 * 4) = pk;
            float4 pd = *(const float4*)(pend + c * K_DIM + k0 + q4 * 4);
            acc[0] *= pd.x; acc[1] *= pd.y; acc[2] *= pd.z; acc[3] *= pd.w;
        } else {
#pragma unroll
            for (int i = 0; i < 4; i++)
                ST[(cloc * V_DIM + v0 + q4 * 4 + i) * K_DIM + k0 + ln15] = f2b(fw(acc[i]));
            float pd = pend[c * K_DIM + k0 + ln15];
#pragma unroll
            for (int i = 0; i < 4; i++) acc[i] *= pd;
        }
#pragma unroll
        for (int s0 = 0; s0 < CHUNK; s0 += 32) {
            bf16x8 a = *(const bf16x8*)(khatT + (long)(k0 + ln15) * T_LEN + c * CHUNK + s0 + q4 * 8);
            bf16x8 b = *(const bf16x8*)(vT + (long)(v0 + ln15) * T_LEN + c * CHUNK + s0 + q4 * 8);
            acc = __builtin_amdgcn_mfma_f32_16x16x32_bf16(a, b, acc, 0, 0, 0);
        }
    }
#pragma unroll
    for (int i = 0; i < 4; i++) {
        int dk = fl ? ln15 : q4 * 4 + i;
        int dv = fl ? q4 * 4 + i : ln15;
        Sio[(long)(k0 + dk) * V_DIM + v0 + dv] = fw(acc[i]);
    }
}

// fp32 [K][V] state -> fp32 output copy
__global__ __launch_bounds__(256) void copy_state_k(const float* __restrict__ S,
                                                    float* __restrict__ out) {
    long i = (long)blockIdx.x * 1024 + threadIdx.x * 4;
    *(float4*)(out + i) = *(const float4*)(S + i);
}

// ---------------------------------------------------------------------------
// Per-chunk output: outs = Qs @ S_c + tril(Qs @ Ks^T) @ V_c. grid 2*CGROUP.
__global__ __launch_bounds__(256) void intra_k(const unsigned short* __restrict__ qs,
                                               const unsigned short* __restrict__ ks,
                                               const unsigned short* __restrict__ vT,
                                               const unsigned short* __restrict__ ST,
                                               unsigned short* __restrict__ outs,
                                               int c_base,
                                               const int* __restrict__ flagp) {
    __shared__ unsigned short Ab[64 * 72];
    int fl = *flagp;
    long cloc = blockIdx.x >> 1;
    int c = c_base + (int)cloc, h = blockIdx.x & 1;
    int lane = threadIdx.x & 63, w = threadIdx.x >> 6;
    int ln15 = lane & 15, q4 = lane >> 4;
    long t0 = (long)c * CHUNK;

    // Stage A: A = Qs @ Ks^T (64x64), causal mask (s <= t), bf16 into LDS
    {
        f32x4 accA[4] = {};
        for (int kk = 0; kk < K_DIM; kk += 32) {
            bf16x8 a = *(const bf16x8*)(qs + (t0 + 16 * w + ln15) * K_DIM + kk + q4 * 8);
#pragma unroll
            for (int j = 0; j < 4; j++) {
                bf16x8 b = *(const bf16x8*)(ks + (t0 + 16 * j + ln15) * K_DIM + kk + q4 * 8);
                accA[j] = __builtin_amdgcn_mfma_f32_16x16x32_bf16(a, b, accA[j], 0, 0, 0);
            }
        }
#pragma unroll
        for (int j = 0; j < 4; j++)
#pragma unroll
            for (int i = 0; i < 4; i++) {
                int dt = fl ? ln15 : q4 * 4 + i;
                int ds = fl ? q4 * 4 + i : ln15;
                int tl = 16 * w + dt;
                int s = 16 * j + ds;
                float av = (s <= tl) ? accA[j][i] : 0.0f;
                Ab[tl * 72 + s] = f2b(fw(av));
            }
    }
    __syncthreads();

    // Stage B: wave handles 64 v-cols. acc = Qs @ S^T + Ab @ V
    int v0 = h * 256 + w * 64;
    f32x4 acc[4][4] = {};
    for (int kk = 0; kk < K_DIM; kk += 32) {
        bf16x8 a[4], b[4];
#pragma unroll
        for (int i = 0; i < 4; i++)
            a[i] = *(const bf16x8*)(qs + (t0 + 16 * i + ln15) * K_DIM + kk + q4 * 8);
#pragma unroll
        for (int j = 0; j < 4; j++)
            b[j] = *(const bf16x8*)(ST + (cloc * V_DIM + v0 + 16 * j + ln15) * K_DIM + kk + q4 * 8);
#pragma unroll
        for (int i = 0; i < 4; i++)
#pragma unroll
            for (int j = 0; j < 4; j++)
                acc[i][j] = __builtin_amdgcn_mfma_f32_16x16x32_bf16(a[i], b[j], acc[i][j], 0, 0, 0);
    }
#pragma unroll
    for (int s0 = 0; s0 < CHUNK; s0 += 32) {
        bf16x8 a[4], b[4];
#pragma unroll
        for (int i = 0; i < 4; i++)
            a[i] = *(const bf16x8*)(Ab + (16 * i + ln15) * 72 + s0 + q4 * 8);
#pragma unroll
        for (int j = 0; j < 4; j++)
            b[j] = *(const bf16x8*)(vT + (long)(v0 + 16 * j + ln15) * T_LEN + t0 + s0 + q4 * 8);
#pragma unroll
        for (int i = 0; i < 4; i++)
#pragma unroll
            for (int j = 0; j < 4; j++)
                acc[i][j] = __builtin_amdgcn_mfma_f32_16x16x32_bf16(a[i], b[j], acc[i][j], 0, 0, 0);
    }
#pragma unroll
    for (int i = 0; i < 4; i++)
#pragma unroll
        for (int j = 0; j < 4; j++)
#pragma unroll
            for (int ii = 0; ii < 4; ii++) {
                int dt = fl ? ln15 : q4 * 4 + ii;
                int dv = fl ? q4 * 4 + ii : ln15;
                outs[(t0 + 16 * i + dt) * V_DIM + v0 + 16 * j + dv] = f2b(fw(acc[i][j][ii]));
            }
}

// ---------------------------------------------------------------------------
extern "C" void kernel_launch(void* const* d_in, const int* in_sizes, int n_in,
                              void* d_out, int out_size, void* d_ws, size_t ws_size,
                              hipStream_t stream) {
    // All inputs fp32 (per reference; confirmed by round-2/3/4 error forensics).
    const float* hs = (const float*)d_in[0];
    const float* Wq = (const float*)d_in[1];
    const float* bq = (const float*)d_in[2];
    const float* Wk = (const float*)d_in[3];
    const float* bk = (const float*)d_in[4];
    const float* Wv = (const float*)d_in[5];
    const float* bv = (const float*)d_in[6];
    const float* Wg = (const float*)d_in[7];
    const float* bg = (const float*)d_in[8];
    const float* Wo = (const float*)d_in[9];
    const float* bo = (const float*)d_in[10];

    float* out = (float*)d_out;  // fp32 output

    // Workspace layout, peak ~84.5 MB (2-pass ST; hsb aliases STb).
    char* ws = (char*)d_ws;
    const size_t MB = 1024 * 1024;
    unsigned short* WqT = (unsigned short*)(ws + 0 * MB);     // 2 MB
    unsigned short* WkT = (unsigned short*)(ws + 2 * MB);     // 2 MB
    unsigned short* WgT = (unsigned short*)(ws + 4 * MB);     // 2 MB
    unsigned short* WvT = (unsigned short*)(ws + 6 * MB);     // 2 MB
    unsigned short* vTb = (unsigned short*)(ws + 0 * MB);     // 8 MB, reuses W{q,k,g,v}T
    unsigned short* WoT = (unsigned short*)(ws + 8 * MB);     // 2 MB
    unsigned short* qb = (unsigned short*)(ws + 10 * MB);     // 8 MB
    unsigned short* kb = (unsigned short*)(ws + 18 * MB);     // 8 MB
    unsigned short* vb = (unsigned short*)(ws + 26 * MB);     // 8 MB
    unsigned short* khatT = (unsigned short*)(ws + 26 * MB);  // 8 MB, reuses vb
    float* gb = (float*)(ws + 34 * MB);                       // 16 MB
    unsigned short* outsb = (unsigned short*)(ws + 34 * MB);  // 8 MB, reuses gb
    float* pend = (float*)(ws + 50 * MB);                     // 256 KB
    int* flags = (int*)(ws + 50 * MB + 256 * 1024);           // [0] = layout flag
    float* Scarry = (float*)(ws + 51 * MB);                   // 1 MB fp32 [K][V]
    unsigned short* STb = (unsigned short*)(ws + 52 * MB);    // 32 MB (CGROUP chunks)
    unsigned short* hsb = (unsigned short*)(ws + 52 * MB);    // 32 MB, dead before scan
    float* fsspare = (float*)(ws + 84 * MB);                  // 1 MB -> peak 85 MB
    (void)ws_size; (void)in_sizes; (void)n_in;

    float* finalst =
        ((long)out_size >= (long)T_LEN * O_DIM + (long)K_DIM * V_DIM)
            ? out + (long)T_LEN * O_DIM
            : fsspare;

    dim3 b256(256);
    hipMemsetAsync(flags, 0, 16, stream);
    probe_k<<<dim3(1), dim3(64), 0, stream>>>(flags);
    // canonicalize fp32 inputs to bf16
    conv2bf_k<<<dim3(8192), b256, 0, stream>>>(hs, hsb, (long)T_LEN * H_DIM);
    transpose_k<1><<<dim3(H_DIM / 32, K_DIM / 32), b256, 0, stream>>>(Wq, WqT, H_DIM, K_DIM);
    transpose_k<1><<<dim3(H_DIM / 32, K_DIM / 32), b256, 0, stream>>>(Wk, WkT, H_DIM, K_DIM);
    transpose_k<1><<<dim3(H_DIM / 32, V_DIM / 32), b256, 0, stream>>>(Wv, WvT, H_DIM, V_DIM);
    transpose_k<1><<<dim3(H_DIM / 32, K_DIM / 32), b256, 0, stream>>>(Wg, WgT, H_DIM, K_DIM);
    transpose_k<1><<<dim3(V_DIM / 32, O_DIM / 32), b256, 0, stream>>>(Wo, WoT, V_DIM, O_DIM);
    // projections (biases read fp32 directly)
    gemm_bt<0, unsigned short><<<dim3(T_LEN / 128, K_DIM / 128), b256, 0, stream>>>(
        hsb, WqT, bq, qb, T_LEN, K_DIM, H_DIM, flags);
    gemm_bt<1, unsigned short><<<dim3(T_LEN / 128, K_DIM / 128), b256, 0, stream>>>(
        hsb, WkT, bk, kb, T_LEN, K_DIM, H_DIM, flags);
    gemm_bt<1, float><<<dim3(T_LEN / 128, K_DIM / 128), b256, 0, stream>>>(
        hsb, WgT, bg, gb, T_LEN, K_DIM, H_DIM, flags);
    gemm_bt<0, unsigned short><<<dim3(T_LEN / 128, V_DIM / 128), b256, 0, stream>>>(
        hsb, WvT, bv, vb, T_LEN, V_DIM, H_DIM, flags);
    // v transpose (bf16 source)
    transpose_k<0><<<dim3(T_LEN / 32, V_DIM / 32), b256, 0, stream>>>(vb, vTb, T_LEN, V_DIM);
    cumprod_k<<<dim3(NCHUNK, K_DIM / 256), b256, 0, stream>>>(gb, qb, kb, khatT, pend);
    // 2-pass chunk scan + intra
    hipMemsetAsync(Scarry, 0, (size_t)K_DIM * V_DIM * 4, stream);
    scan_k<<<dim3(256), b256, 0, stream>>>(khatT, vTb, pend, STb, Scarry, 0, CGROUP, flags);
    intra_k<<<dim3(2 * CGROUP), b256, 0, stream>>>(qb, kb, vTb, STb, outsb, 0, flags);
    scan_k<<<dim3(256), b256, 0, stream>>>(khatT, vTb, pend, STb, Scarry, CGROUP, NCHUNK, flags);
    intra_k<<<dim3(2 * CGROUP), b256, 0, stream>>>(qb, kb, vTb, STb, outsb, CGROUP, flags);
    copy_state_k<<<dim3((K_DIM * V_DIM) / 1024), b256, 0, stream>>>(Scarry, finalst);
    // final projection -> fp32 d_out
    gemm_bt<0, float><<<dim3(T_LEN / 128, O_DIM / 128), b256, 0, stream>>>(
        outsb, WoT, bo, out, T_LEN, O_DIM, V_DIM, flags);
}

// Round 6
// 482.194 us; speedup vs baseline: 1.1720x; 1.1720x over previous
//
#include <hip/hip_runtime.h>

// Problem dims
#define T_LEN 8192
#define H_DIM 2048
#define K_DIM 512
#define V_DIM 512
#define O_DIM 2048
#define CHUNK 64
#define NCHUNK 128   // T_LEN / CHUNK
#define CGROUP 64    // chunks per scan/intra pass (2 passes)

typedef short bf16x8 __attribute__((ext_vector_type(8)));
typedef float f32x4 __attribute__((ext_vector_type(4)));

typedef const __attribute__((address_space(1))) void* gptr1_t;
typedef __attribute__((address_space(3))) void* lptr3_t;

__device__ __forceinline__ float b2f(unsigned short u) {
    unsigned int i = ((unsigned int)u) << 16;
    float f;
    __builtin_memcpy(&f, &i, 4);
    return f;
}
__device__ __forceinline__ unsigned short f2b(float f) {
    unsigned int i;
    __builtin_memcpy(&i, &f, 4);
    unsigned int r = (i + 0x7FFFu + ((i >> 16) & 1u)) >> 16;  // RNE
    return (unsigned short)r;
}
// NaN/inf firewall
__device__ __forceinline__ float fw(float v) {
    return fminf(fmaxf(v, -1e30f), 1e30f);
}

// ---------------------------------------------------------------------------
// fp32 -> bf16 pack, 8 elements/thread. N multiple of 8.
__global__ __launch_bounds__(256) void conv2bf_k(const float* __restrict__ in,
                                                 unsigned short* __restrict__ out,
                                                 long N) {
    long i = ((long)blockIdx.x * 256 + threadIdx.x) * 8;
    if (i >= N) return;
    unsigned int w[4];
#pragma unroll
    for (int u = 0; u < 4; u++) {
        unsigned short lo = f2b(in[i + 2 * u]);
        unsigned short hi = f2b(in[i + 2 * u + 1]);
        w[u] = (unsigned int)lo | ((unsigned int)hi << 16);
    }
    uint4 pk; pk.x = w[0]; pk.y = w[1]; pk.z = w[2]; pk.w = w[3];
    *(uint4*)(out + i) = pk;
}

// ---------------------------------------------------------------------------
// Runtime C/D-layout probe for mfma_f32_16x16x32_bf16 (vs our load convention).
__global__ __launch_bounds__(64) void probe_k(int* __restrict__ flag) {
    __shared__ unsigned short As[16 * 32];
    __shared__ unsigned short Bs[16 * 32];
    int tid = threadIdx.x;
    for (int idx = tid; idx < 512; idx += 64) {
        int r = idx >> 5, c = idx & 31;
        float av = (c == 0) ? (float)(r + 1) : (c == 1 ? 1.0f : 0.0f);
        float bv = (c == 0) ? 1.0f : (c == 1 ? (float)(1024 * (r + 1)) : 0.0f);
        As[r * 32 + c] = f2b(av);
        Bs[r * 32 + c] = f2b(bv);
    }
    __syncthreads();
    int ln15 = tid & 15, q4 = (tid & 63) >> 4;
    bf16x8 a = *(const bf16x8*)(As + ln15 * 32 + q4 * 8);
    bf16x8 b = *(const bf16x8*)(Bs + ln15 * 32 + q4 * 8);
    f32x4 acc = {0.f, 0.f, 0.f, 0.f};
    acc = __builtin_amdgcn_mfma_f32_16x16x32_bf16(a, b, acc, 0, 0, 0);
    bool h0 = true, h1 = true;
#pragma unroll
    for (int i = 0; i < 4; i++) {
        float e0 = (float)((q4 * 4 + i + 1) + 1024 * (ln15 + 1));
        float e1 = (float)((ln15 + 1) + 1024 * (q4 * 4 + i + 1));
        h0 = h0 && (acc[i] == e0);
        h1 = h1 && (acc[i] == e1);
    }
    unsigned long long b0 = __ballot(h0 ? 1 : 0);
    unsigned long long b1 = __ballot(h1 ? 1 : 0);
    if (tid == 0) *flag = (b0 == ~0ull) ? 0 : ((b1 == ~0ull) ? 1 : 0);
}

// ---------------------------------------------------------------------------
// Transpose to bf16: in[R][C] -> out[C][R]. DF=1: in fp32; DF=0: bf16.
template <int DF>
__global__ __launch_bounds__(256) void transpose_k(const void* __restrict__ in,
                                                   unsigned short* __restrict__ out,
                                                   int R, int C) {
    __shared__ unsigned short tile[32][33];
    int br = blockIdx.x, bc = blockIdx.y;
    int tc = threadIdx.x & 31, tr = threadIdx.x >> 5;
#pragma unroll
    for (int i = 0; i < 4; i++) {
        int r = tr + 8 * i;
        long idx = (long)(br * 32 + r) * C + bc * 32 + tc;
        tile[r][tc] = DF ? f2b(((const float*)in)[idx]) : ((const unsigned short*)in)[idx];
    }
    __syncthreads();
#pragma unroll
    for (int i = 0; i < 4; i++) {
        int r = tr + 8 * i;
        out[(long)(bc * 32 + r) * R + br * 32 + tc] = tile[tc][r];
    }
}

// ---------------------------------------------------------------------------
// Fused projection GEMM: A=[T][H] bf16, WT=[2048][H] bf16 (rows: q512|k512|g512|v512).
// grid (T/128, 16). Segment epilogues: q->qb, k->sigmoid kb, g->sigmoid fp32 gb,
// v->vT (written transposed [V][T]). global_load_lds width-16 staging (m97-style).
__global__ __launch_bounds__(256) void proj_gemm_k(const unsigned short* __restrict__ A,
                                                   const unsigned short* __restrict__ WT,
                                                   const float* __restrict__ bq,
                                                   const float* __restrict__ bk,
                                                   const float* __restrict__ bg,
                                                   const float* __restrict__ bv,
                                                   unsigned short* __restrict__ qb,
                                                   unsigned short* __restrict__ kb,
                                                   float* __restrict__ gb,
                                                   unsigned short* __restrict__ vT,
                                                   const int* __restrict__ flagp) {
    __shared__ unsigned short As[128 * 32];
    __shared__ unsigned short Bs[128 * 32];
    int fl = *flagp;
    int tid = threadIdx.x;
    int lane = tid & 63;
    int w = tid >> 6;
    int ln15 = lane & 15, q4 = lane >> 4;
    int wm = w >> 1, wn = w & 1;
    long m0 = (long)blockIdx.x * 128, n0 = (long)blockIdx.y * 128;

    f32x4 acc[4][4] = {};

    for (int kt = 0; kt < H_DIM; kt += 32) {
        __syncthreads();
#pragma unroll
        for (int it = 0; it < 2; it++) {
            int chunk = it * 256 + tid;            // 0..511
            int row = chunk >> 2;                  // 0..127
            int col = (chunk & 3) * 8;             // 0,8,16,24
            const unsigned short* ga = A + (m0 + row) * (long)H_DIM + kt + col;
            const unsigned short* gb_ = WT + (n0 + row) * (long)H_DIM + kt + col;
            __builtin_amdgcn_global_load_lds((gptr1_t)(const void*)ga,
                                             (lptr3_t)(void*)(As + chunk * 8), 16, 0, 0);
            __builtin_amdgcn_global_load_lds((gptr1_t)(const void*)gb_,
                                             (lptr3_t)(void*)(Bs + chunk * 8), 16, 0, 0);
        }
        __syncthreads();
        bf16x8 a[4], b[4];
#pragma unroll
        for (int i = 0; i < 4; i++)
            a[i] = *(const bf16x8*)(As + (wm * 64 + 16 * i + ln15) * 32 + q4 * 8);
#pragma unroll
        for (int j = 0; j < 4; j++)
            b[j] = *(const bf16x8*)(Bs + (wn * 64 + 16 * j + ln15) * 32 + q4 * 8);
#pragma unroll
        for (int i = 0; i < 4; i++)
#pragma unroll
            for (int j = 0; j < 4; j++)
                acc[i][j] = __builtin_amdgcn_mfma_f32_16x16x32_bf16(a[i], b[j], acc[i][j], 0, 0, 0);
    }

    int seg = (int)(n0 >> 9);        // 0=q 1=k 2=g 3=v
    int nl0 = (int)(n0 & 511);
    const float* bias = seg == 0 ? bq : seg == 1 ? bk : seg == 2 ? bg : bv;

    if (seg == 3 && fl == 0) {
        // v written transposed, 8B-packed (4 consecutive m per lane)
#pragma unroll
        for (int i = 0; i < 4; i++)
#pragma unroll
            for (int j = 0; j < 4; j++) {
                int nl = nl0 + wn * 64 + 16 * j + ln15;
                float bsv = bias[nl];
                long mb = m0 + wm * 64 + 16 * i + q4 * 4;
                unsigned short h0 = f2b(fw(acc[i][j][0] + bsv));
                unsigned short h1 = f2b(fw(acc[i][j][1] + bsv));
                unsigned short h2 = f2b(fw(acc[i][j][2] + bsv));
                unsigned short h3 = f2b(fw(acc[i][j][3] + bsv));
                uint2 pk;
                pk.x = (unsigned int)h0 | ((unsigned int)h1 << 16);
                pk.y = (unsigned int)h2 | ((unsigned int)h3 << 16);
                *(uint2*)(vT + (long)nl * T_LEN + mb) = pk;
            }
    } else {
#pragma unroll
        for (int i = 0; i < 4; i++)
#pragma unroll
            for (int j = 0; j < 4; j++)
#pragma unroll
                for (int ii = 0; ii < 4; ii++) {
                    int dm = fl ? ln15 : q4 * 4 + ii;
                    int dn = fl ? q4 * 4 + ii : ln15;
                    long m = m0 + wm * 64 + 16 * i + dm;
                    int nl = nl0 + wn * 64 + 16 * j + dn;
                    float v = fw(acc[i][j][ii] + bias[nl]);
                    if (seg == 1 || seg == 2) v = 1.0f / (1.0f + __expf(-v));
                    if (seg == 0)
                        qb[m * K_DIM + nl] = f2b(v);
                    else if (seg == 1)
                        kb[m * K_DIM + nl] = f2b(v);
                    else if (seg == 2)
                        gb[m * K_DIM + nl] = v;
                    else
                        vT[(long)nl * T_LEN + m] = f2b(v);
                }
    }
}

// ---------------------------------------------------------------------------
// Generic 128x128 bf16 GEMM (B^T input), fp32 out, global_load_lds staging.
__global__ __launch_bounds__(256) void gemm_f32_k(const unsigned short* __restrict__ A,
                                                  const unsigned short* __restrict__ BT,
                                                  const float* __restrict__ bias,
                                                  float* __restrict__ out,
                                                  int M, int N, int K,
                                                  const int* __restrict__ flagp) {
    __shared__ unsigned short As[128 * 32];
    __shared__ unsigned short Bs[128 * 32];
    int fl = *flagp;
    int tid = threadIdx.x;
    int lane = tid & 63;
    int w = tid >> 6;
    int ln15 = lane & 15, q4 = lane >> 4;
    int wm = w >> 1, wn = w & 1;
    long m0 = (long)blockIdx.x * 128, n0 = (long)blockIdx.y * 128;

    f32x4 acc[4][4] = {};

    for (int kt = 0; kt < K; kt += 32) {
        __syncthreads();
#pragma unroll
        for (int it = 0; it < 2; it++) {
            int chunk = it * 256 + tid;
            int row = chunk >> 2;
            int col = (chunk & 3) * 8;
            const unsigned short* ga = A + (m0 + row) * (long)K + kt + col;
            const unsigned short* gbp = BT + (n0 + row) * (long)K + kt + col;
            __builtin_amdgcn_global_load_lds((gptr1_t)(const void*)ga,
                                             (lptr3_t)(void*)(As + chunk * 8), 16, 0, 0);
            __builtin_amdgcn_global_load_lds((gptr1_t)(const void*)gbp,
                                             (lptr3_t)(void*)(Bs + chunk * 8), 16, 0, 0);
        }
        __syncthreads();
        bf16x8 a[4], b[4];
#pragma unroll
        for (int i = 0; i < 4; i++)
            a[i] = *(const bf16x8*)(As + (wm * 64 + 16 * i + ln15) * 32 + q4 * 8);
#pragma unroll
        for (int j = 0; j < 4; j++)
            b[j] = *(const bf16x8*)(Bs + (wn * 64 + 16 * j + ln15) * 32 + q4 * 8);
#pragma unroll
        for (int i = 0; i < 4; i++)
#pragma unroll
            for (int j = 0; j < 4; j++)
                acc[i][j] = __builtin_amdgcn_mfma_f32_16x16x32_bf16(a[i], b[j], acc[i][j], 0, 0, 0);
    }

#pragma unroll
    for (int i = 0; i < 4; i++)
#pragma unroll
        for (int j = 0; j < 4; j++)
#pragma unroll
            for (int ii = 0; ii < 4; ii++) {
                int dm = fl ? ln15 : q4 * 4 + ii;
                int dn = fl ? q4 * 4 + ii : ln15;
                long m = m0 + wm * 64 + 16 * i + dm;
                long n = n0 + wn * 64 + 16 * j + dn;
                out[m * N + n] = fw(acc[i][j][ii] + bias[n]);
            }
}

// ---------------------------------------------------------------------------
// Per (chunk, dim): cumulative gate products. In-place q->q*P, k->k/P; writes
// khatT[d][t] = k * Pend/P (transposed), pend[c][d].
__global__ __launch_bounds__(256) void cumprod_k(const float* __restrict__ g,
                                                 unsigned short* __restrict__ q,
                                                 unsigned short* __restrict__ k,
                                                 unsigned short* __restrict__ khatT,
                                                 float* __restrict__ pend) {
    int c = blockIdx.x;
    int d = blockIdx.y * 256 + threadIdx.x;
    long base = (long)c * CHUNK * K_DIM + d;
    float P = 1.0f;
    for (int s = 0; s < CHUNK; s++) P = fmaxf(P * g[base + (long)s * K_DIM], 1e-37f);
    pend[c * K_DIM + d] = P;
    float Pend = P;
    P = 1.0f;
    for (int s8 = 0; s8 < CHUNK; s8 += 8) {
        unsigned int packed[4];
#pragma unroll
        for (int u = 0; u < 8; u++) {
            int s = s8 + u;
            long idx = base + (long)s * K_DIM;
            P = fmaxf(P * g[idx], 1e-37f);
            float qv = fw(b2f(q[idx]) * P);
            q[idx] = f2b(qv);
            float kv = b2f(k[idx]);
            float kt = kv / P;
            kt = fmaxf(fminf(kt, 3e37f), -3e37f);
            k[idx] = f2b(kt);
            float ratio = Pend / P;  // in (0,1]
            unsigned short kh = f2b(fw(kv * ratio));
            if (u & 1)
                packed[u >> 1] |= ((unsigned int)kh) << 16;
            else
                packed[u >> 1] = kh;
        }
        uint4 pk;
        pk.x = packed[0]; pk.y = packed[1]; pk.z = packed[2]; pk.w = packed[3];
        *(uint4*)(khatT + (long)d * T_LEN + c * CHUNK + s8) = pk;
    }
}

// ---------------------------------------------------------------------------
// Sequential chunk scan over [c0, cn). fp32 state in Sio [K][V]; per chunk
// writes bf16 S-before into ST[(c-c0)] ([v][k], k contiguous).
__global__ __launch_bounds__(256) void scan_k(const unsigned short* __restrict__ khatT,
                                              const unsigned short* __restrict__ vT,
                                              const float* __restrict__ pend,
                                              unsigned short* __restrict__ ST,
                                              float* __restrict__ Sio,
                                              int c0, int cn,
                                              const int* __restrict__ flagp) {
    int fl = *flagp;
    int lane = threadIdx.x & 63, w = threadIdx.x >> 6;
    int ln15 = lane & 15, q4 = lane >> 4;
    int k0 = (blockIdx.x & 15) * 32 + (w & 1) * 16;
    int v0 = (blockIdx.x >> 4) * 32 + (w >> 1) * 16;
    f32x4 acc;
#pragma unroll
    for (int i = 0; i < 4; i++) {
        int dk = fl ? ln15 : q4 * 4 + i;
        int dv = fl ? q4 * 4 + i : ln15;
        acc[i] = Sio[(long)(k0 + dk) * V_DIM + v0 + dv];
    }
    for (int c = c0; c < cn; c++) {
        long cloc = c - c0;
        if (!fl) {
            uint2 pk;
            pk.x = (unsigned int)f2b(fw(acc[0])) | ((unsigned int)f2b(fw(acc[1])) << 16);
            pk.y = (unsigned int)f2b(fw(acc[2])) | ((unsigned int)f2b(fw(acc[3])) << 16);
            *(uint2*)(ST + (cloc * V_DIM + v0 + ln15) * K_DIM + k0 + q4 * 4) = pk;
            float4 pd = *(const float4*)(pend + c * K_DIM + k0 + q4 * 4);
            acc[0] *= pd.x; acc[1] *= pd.y; acc[2] *= pd.z; acc[3] *= pd.w;
        } else {
#pragma unroll
            for (int i = 0; i < 4; i++)
                ST[(cloc * V_DIM + v0 + q4 * 4 + i) * K_DIM + k0 + ln15] = f2b(fw(acc[i]));
            float pd = pend[c * K_DIM + k0 + ln15];
#pragma unroll
            for (int i = 0; i < 4; i++) acc[i] *= pd;
        }
#pragma unroll
        for (int s0 = 0; s0 < CHUNK; s0 += 32) {
            bf16x8 a = *(const bf16x8*)(khatT + (long)(k0 + ln15) * T_LEN + c * CHUNK + s0 + q4 * 8);
            bf16x8 b = *(const bf16x8*)(vT + (long)(v0 + ln15) * T_LEN + c * CHUNK + s0 + q4 * 8);
            acc = __builtin_amdgcn_mfma_f32_16x16x32_bf16(a, b, acc, 0, 0, 0);
        }
    }
#pragma unroll
    for (int i = 0; i < 4; i++) {
        int dk = fl ? ln15 : q4 * 4 + i;
        int dv = fl ? q4 * 4 + i : ln15;
        Sio[(long)(k0 + dk) * V_DIM + v0 + dv] = fw(acc[i]);
    }
}

// fp32 [K][V] state -> fp32 output copy
__global__ __launch_bounds__(256) void copy_state_k(const float* __restrict__ S,
                                                    float* __restrict__ out) {
    long i = (long)blockIdx.x * 1024 + threadIdx.x * 4;
    *(float4*)(out + i) = *(const float4*)(S + i);
}

// ---------------------------------------------------------------------------
// Per-chunk output: outs = Qs @ S_c + tril(Qs @ Ks^T) @ V_c. grid 2*CGROUP.
__global__ __launch_bounds__(256) void intra_k(const unsigned short* __restrict__ qs,
                                               const unsigned short* __restrict__ ks,
                                               const unsigned short* __restrict__ vT,
                                               const unsigned short* __restrict__ ST,
                                               unsigned short* __restrict__ outs,
                                               int c_base,
                                               const int* __restrict__ flagp) {
    __shared__ unsigned short Ab[64 * 72];
    int fl = *flagp;
    long cloc = blockIdx.x >> 1;
    int c = c_base + (int)cloc, h = blockIdx.x & 1;
    int lane = threadIdx.x & 63, w = threadIdx.x >> 6;
    int ln15 = lane & 15, q4 = lane >> 4;
    long t0 = (long)c * CHUNK;

    // Stage A: A = Qs @ Ks^T (64x64), causal mask (s <= t), bf16 into LDS
    {
        f32x4 accA[4] = {};
        for (int kk = 0; kk < K_DIM; kk += 32) {
            bf16x8 a = *(const bf16x8*)(qs + (t0 + 16 * w + ln15) * K_DIM + kk + q4 * 8);
#pragma unroll
            for (int j = 0; j < 4; j++) {
                bf16x8 b = *(const bf16x8*)(ks + (t0 + 16 * j + ln15) * K_DIM + kk + q4 * 8);
                accA[j] = __builtin_amdgcn_mfma_f32_16x16x32_bf16(a, b, accA[j], 0, 0, 0);
            }
        }
#pragma unroll
        for (int j = 0; j < 4; j++)
#pragma unroll
            for (int i = 0; i < 4; i++) {
                int dt = fl ? ln15 : q4 * 4 + i;
                int ds = fl ? q4 * 4 + i : ln15;
                int tl = 16 * w + dt;
                int s = 16 * j + ds;
                float av = (s <= tl) ? accA[j][i] : 0.0f;
                Ab[tl * 72 + s] = f2b(fw(av));
            }
    }
    __syncthreads();

    // Stage B: wave handles 64 v-cols. acc = Qs @ S^T + Ab @ V
    int v0 = h * 256 + w * 64;
    f32x4 acc[4][4] = {};
    for (int kk = 0; kk < K_DIM; kk += 32) {
        bf16x8 a[4], b[4];
#pragma unroll
        for (int i = 0; i < 4; i++)
            a[i] = *(const bf16x8*)(qs + (t0 + 16 * i + ln15) * K_DIM + kk + q4 * 8);
#pragma unroll
        for (int j = 0; j < 4; j++)
            b[j] = *(const bf16x8*)(ST + (cloc * V_DIM + v0 + 16 * j + ln15) * K_DIM + kk + q4 * 8);
#pragma unroll
        for (int i = 0; i < 4; i++)
#pragma unroll
            for (int j = 0; j < 4; j++)
                acc[i][j] = __builtin_amdgcn_mfma_f32_16x16x32_bf16(a[i], b[j], acc[i][j], 0, 0, 0);
    }
#pragma unroll
    for (int s0 = 0; s0 < CHUNK; s0 += 32) {
        bf16x8 a[4], b[4];
#pragma unroll
        for (int i = 0; i < 4; i++)
            a[i] = *(const bf16x8*)(Ab + (16 * i + ln15) * 72 + s0 + q4 * 8);
#pragma unroll
        for (int j = 0; j < 4; j++)
            b[j] = *(const bf16x8*)(vT + (long)(v0 + 16 * j + ln15) * T_LEN + t0 + s0 + q4 * 8);
#pragma unroll
        for (int i = 0; i < 4; i++)
#pragma unroll
            for (int j = 0; j < 4; j++)
                acc[i][j] = __builtin_amdgcn_mfma_f32_16x16x32_bf16(a[i], b[j], acc[i][j], 0, 0, 0);
    }
#pragma unroll
    for (int i = 0; i < 4; i++)
#pragma unroll
        for (int j = 0; j < 4; j++)
#pragma unroll
            for (int ii = 0; ii < 4; ii++) {
                int dt = fl ? ln15 : q4 * 4 + ii;
                int dv = fl ? q4 * 4 + ii : ln15;
                outs[(t0 + 16 * i + dt) * V_DIM + v0 + 16 * j + dv] = f2b(fw(acc[i][j][ii]));
            }
}

// ---------------------------------------------------------------------------
extern "C" void kernel_launch(void* const* d_in, const int* in_sizes, int n_in,
                              void* d_out, int out_size, void* d_ws, size_t ws_size,
                              hipStream_t stream) {
    const float* hs = (const float*)d_in[0];
    const float* Wq = (const float*)d_in[1];
    const float* bq = (const float*)d_in[2];
    const float* Wk = (const float*)d_in[3];
    const float* bk = (const float*)d_in[4];
    const float* Wv = (const float*)d_in[5];
    const float* bv = (const float*)d_in[6];
    const float* Wg = (const float*)d_in[7];
    const float* bg = (const float*)d_in[8];
    const float* Wo = (const float*)d_in[9];
    const float* bo = (const float*)d_in[10];

    float* out = (float*)d_out;  // fp32 output

    // Workspace layout, peak 93 MB (<= 116 MB demonstrated safe in r1/r2).
    char* ws = (char*)d_ws;
    const size_t MB = 1024 * 1024;
    unsigned short* WT = (unsigned short*)(ws + 0 * MB);      // 8 MB: q|k|g|v transposed [2048][2048]
    unsigned short* WoT = (unsigned short*)(ws + 8 * MB);     // 2 MB
    unsigned short* qb = (unsigned short*)(ws + 10 * MB);     // 8 MB
    unsigned short* kb = (unsigned short*)(ws + 18 * MB);     // 8 MB
    unsigned short* vTb = (unsigned short*)(ws + 26 * MB);    // 8 MB (written by proj gemm)
    float* gb = (float*)(ws + 34 * MB);                       // 16 MB fp32
    unsigned short* outsb = (unsigned short*)(ws + 34 * MB);  // 8 MB, reuses gb after cumprod
    unsigned short* khatT = (unsigned short*)(ws + 50 * MB);  // 8 MB
    float* pend = (float*)(ws + 58 * MB);                     // 256 KB
    int* flags = (int*)(ws + 58 * MB + 256 * 1024);           // [0] layout flag
    float* Scarry = (float*)(ws + 59 * MB);                   // 1 MB fp32 [K][V]
    unsigned short* STb = (unsigned short*)(ws + 60 * MB);    // 32 MB (CGROUP chunks)
    unsigned short* hsb = (unsigned short*)(ws + 60 * MB);    // 32 MB, dead before scan
    float* fsspare = (float*)(ws + 92 * MB);                  // 1 MB -> peak 93 MB
    (void)ws_size; (void)in_sizes; (void)n_in;

    float* finalst =
        ((long)out_size >= (long)T_LEN * O_DIM + (long)K_DIM * V_DIM)
            ? out + (long)T_LEN * O_DIM
            : fsspare;

    dim3 b256(256);
    hipMemsetAsync(flags, 0, 16, stream);
    probe_k<<<dim3(1), dim3(64), 0, stream>>>(flags);
    // canonicalize fp32 inputs to bf16
    conv2bf_k<<<dim3(8192), b256, 0, stream>>>(hs, hsb, (long)T_LEN * H_DIM);
    // weight transposes into the stacked WT (q|k|g|v) and WoT
    transpose_k<1><<<dim3(H_DIM / 32, K_DIM / 32), b256, 0, stream>>>(Wq, WT + 0 * 512 * H_DIM, H_DIM, K_DIM);
    transpose_k<1><<<dim3(H_DIM / 32, K_DIM / 32), b256, 0, stream>>>(Wk, WT + 1 * 512 * H_DIM, H_DIM, K_DIM);
    transpose_k<1><<<dim3(H_DIM / 32, K_DIM / 32), b256, 0, stream>>>(Wg, WT + 2 * 512 * H_DIM, H_DIM, K_DIM);
    transpose_k<1><<<dim3(H_DIM / 32, V_DIM / 32), b256, 0, stream>>>(Wv, WT + 3 * 512 * H_DIM, H_DIM, V_DIM);
    transpose_k<1><<<dim3(V_DIM / 32, O_DIM / 32), b256, 0, stream>>>(Wo, WoT, V_DIM, O_DIM);
    // fused q/k/g/v projection (v written transposed)
    proj_gemm_k<<<dim3(T_LEN / 128, 16), b256, 0, stream>>>(
        hsb, WT, bq, bk, bg, bv, qb, kb, gb, vTb, flags);
    // gate cumulative products
    cumprod_k<<<dim3(NCHUNK, K_DIM / 256), b256, 0, stream>>>(gb, qb, kb, khatT, pend);
    // 2-pass chunk scan + intra
    hipMemsetAsync(Scarry, 0, (size_t)K_DIM * V_DIM * 4, stream);
    scan_k<<<dim3(256), b256, 0, stream>>>(khatT, vTb, pend, STb, Scarry, 0, CGROUP, flags);
    intra_k<<<dim3(2 * CGROUP), b256, 0, stream>>>(qb, kb, vTb, STb, outsb, 0, flags);
    scan_k<<<dim3(256), b256, 0, stream>>>(khatT, vTb, pend, STb, Scarry, CGROUP, NCHUNK, flags);
    intra_k<<<dim3(2 * CGROUP), b256, 0, stream>>>(qb, kb, vTb, STb, outsb, CGROUP, flags);
    copy_state_k<<<dim3((K_DIM * V_DIM) / 1024), b256, 0, stream>>>(Scarry, finalst);
    // final projection -> fp32 d_out
    gemm_f32_k<<<dim3(T_LEN / 128, O_DIM / 128), b256, 0, stream>>>(
        outsb, WoT, bo, out, T_LEN, O_DIM, V_DIM, flags);
}